// Round 9
// baseline (78.815 us; speedup 1.0000x reference)
//
#include <hip/hip_runtime.h>
#include <hip/hip_cooperative_groups.h>

namespace cg = cooperative_groups;

// Problem constants (from the reference)
#define BB   16
#define LL   512
#define KNB  48
#define DIN_ 640
#define H1_  512
#define H2_  256
#define NBLK 64
#define NTH  256

// padded LDS strides (avoid all-b-lanes-same-bank: 640%32==0, 512%32==0)
#define X0S  641
#define X1S  513

__device__ __forceinline__ float nz(float x) { return x == x ? x : 0.0f; }

__device__ __forceinline__ float wave_sum(float v) {
  #pragma unroll
  for (int m = 32; m >= 1; m >>= 1) v += __shfl_xor(v, m);
  return v;
}

// ---------------------------------------------------------------------------
// Cooperative single-launch pipeline, 64 blocks x 256 threads.
//  A (blocks 0..15): rank (ballot/popcount, exact lax.top_k stable ties),
//     640-dim masked-mean embedding, LayerNorm+ReLU -> x0[16,640] in ws.
//  B (all 64): FC1 640->512; block g owns cols [8g,8g+8) for ALL batches ->
//     W1 is read exactly once across the grid (20KB/block) instead of
//     1.25MB per CU.  x0 staged in LDS (stride 641).  Row-halved, 2 thr/out.
//  C (all 64): FC2 512->256 + W3 dot; block g owns cols [4g,4g+4); row-
//     quartered.  Per-(block,batch) partial -> ws.
//  D (blocks 0..15): sum 64 partials + b3 -> out[b].
// ---------------------------------------------------------------------------
__global__ __launch_bounds__(NTH) void k_coop(
    const float* __restrict__ X,      // [B,L,4,3]
    const int*   __restrict__ mpos,   // [B,2]
    const int*   __restrict__ mwt,    // [B,2]
    const int*   __restrict__ mmut,   // [B,2]
    const float* __restrict__ hid1,   // [B,L,128]
    const float* __restrict__ hid2,   // [B,L,128]
    const float* __restrict__ memb,   // [B,L,128]
    const float* __restrict__ edges,  // [B,L,48,128]
    const float* __restrict__ Wse,    // [21,128]
    const float* __restrict__ ln_g,   // [640]
    const float* __restrict__ ln_b,   // [640]
    const float* __restrict__ W1,     // [640,512]
    const float* __restrict__ b1,     // [512]
    const float* __restrict__ W2,     // [512,256]
    const float* __restrict__ b2,     // [256]
    const float* __restrict__ W3,     // [256,1]
    const float* __restrict__ b3,     // [1]
    float* __restrict__ ws,           // scratch
    float* __restrict__ out)          // [16]
{
  cg::grid_group grid = cg::this_grid();
  const int g    = blockIdx.x;
  const int t    = threadIdx.x;
  const int wid  = t >> 6;   // 0..3
  const int lane = t & 63;

  float* x0w = ws;               // [16][640]
  float* x1w = x0w + BB * DIN_;  // [16][512]
  float* pw  = x1w + BB * H1_;   // [64][16]

  __shared__ float sbuf[BB * X0S];  // 16*641 floats (union: A embed / B x0 / C x1)
  __shared__ float s_p[NTH];
  __shared__ float s_small[16];
  __shared__ int   s_cnt[8];

  // ================= Phase A =================
  if (g < BB) {
    const int b = g;
    const int p[2]  = { mpos[b * 2 + 0], mpos[b * 2 + 1] };
    const int mu[2] = { mmut[b * 2 + 0], mmut[b * 2 + 1] };
    const int wt[2] = { mwt[b * 2 + 0],  mwt[b * 2 + 1]  };

    float3 ca[2];
    #pragma unroll
    for (int m = 0; m < 2; ++m) {
      const float* a = X + (((size_t)(b * LL + p[m])) * 4 + 1) * 3;
      ca[m] = make_float3(nz(a[0]), nz(a[1]), nz(a[2]));
    }

    // ranks: each thread covers residues j=t and j=t+256
    {
      const float dx = ca[0].x - ca[1].x, dy = ca[0].y - ca[1].y, dz = ca[0].z - ca[1].z;
      const float dq = sqrtf(dx * dx + dy * dy + dz * dz + 1e-6f);
      bool pr0[2], pr1[2];
      #pragma unroll
      for (int h = 0; h < 2; ++h) {
        const int j = t + h * NTH;
        const float* a = X + (((size_t)(b * LL + j)) * 4 + 1) * 3;
        const float jx = nz(a[0]), jy = nz(a[1]), jz = nz(a[2]);
        const float e0x = jx - ca[0].x, e0y = jy - ca[0].y, e0z = jz - ca[0].z;
        const float d0  = sqrtf(e0x * e0x + e0y * e0y + e0z * e0z + 1e-6f);
        const float e1x = jx - ca[1].x, e1y = jy - ca[1].y, e1z = jz - ca[1].z;
        const float d1  = sqrtf(e1x * e1x + e1y * e1y + e1z * e1z + 1e-6f);
        pr0[h] = (d0 < dq) || (d0 == dq && j < p[1]);
        pr1[h] = (d1 < dq) || (d1 == dq && j < p[0]);
      }
      const int c0 = __popcll(__ballot(pr0[0])) + __popcll(__ballot(pr0[1]));
      const int c1 = __popcll(__ballot(pr1[0])) + __popcll(__ballot(pr1[1]));
      if (lane == 0) { s_cnt[wid] = c0; s_cnt[4 + wid] = c1; }
    }
    __syncthreads();
    const int rk[2] = { s_cnt[0] + s_cnt[1] + s_cnt[2] + s_cnt[3],
                        s_cnt[4] + s_cnt[5] + s_cnt[6] + s_cnt[7] };

    const int v0 = ((p[0] + wt[0] + mu[0]) != 0) ? 1 : 0;
    const int v1 = ((p[1] + wt[1] + mu[1]) != 0) ? 1 : 0;
    const float denom = fmaxf((float)(v0 + v1), 1.0f);
    const int vv[2] = { v0, v1 };

    // masked-mean embedding into sbuf[0..640)
    for (int d = t; d < DIN_; d += NTH) {
      float v = 0.0f;
      #pragma unroll
      for (int m = 0; m < 2; ++m) {
        if (!vv[m]) continue;
        const int base = p[m];
        float e;
        if (d < 128)      e = hid1[(size_t)(b * LL + base) * 128 + d];
        else if (d < 256) e = hid2[(size_t)(b * LL + base) * 128 + (d - 128)];
        else if (d < 384) e = memb[(size_t)(b * LL + base) * 128 + (d - 256)];
        else if (d < 512) e = Wse[mu[m] * 128 + (d - 384)];
        else              e = (rk[m] < KNB)
                                ? edges[(((size_t)(b * LL + base)) * KNB + rk[m]) * 128 + (d - 512)]
                                : 0.0f;
        v += e;
      }
      sbuf[d] = v / denom;
    }
    __syncthreads();

    // LayerNorm
    float ps = 0.0f;
    for (int d = t; d < DIN_; d += NTH) ps += sbuf[d];
    ps = wave_sum(ps);
    if (lane == 0) s_small[wid] = ps;
    __syncthreads();
    const float mu_ = (s_small[0] + s_small[1] + s_small[2] + s_small[3]) / (float)DIN_;

    float pv = 0.0f;
    for (int d = t; d < DIN_; d += NTH) { const float z = sbuf[d] - mu_; pv += z * z; }
    pv = wave_sum(pv);
    if (lane == 0) s_small[8 + wid] = pv;
    __syncthreads();
    const float var = (s_small[8] + s_small[9] + s_small[10] + s_small[11]) / (float)DIN_;
    const float inv = 1.0f / sqrtf(var + 1e-5f);

    for (int d = t; d < DIN_; d += NTH)
      x0w[b * DIN_ + d] = fmaxf((sbuf[d] - mu_) * inv * ln_g[d] + ln_b[d], 0.0f);
  }
  grid.sync();

  // ================= Phase B: FC1 =================
  // stage x0 (all batches) into LDS at stride X0S
  for (int b = 0; b < BB; ++b)
    for (int d = t; d < DIN_; d += NTH)
      sbuf[b * X0S + d] = x0w[b * DIN_ + d];
  __syncthreads();
  {
    const int h   = t >> 7;          // row half 0/1 (rows h*320 .. +320)
    const int rem = t & 127;
    const int b   = rem >> 3;        // batch 0..15
    const int ci  = rem & 7;
    const int c   = g * 8 + ci;      // output column
    const float* xp = sbuf + b * X0S + h * 320;
    const float* wp = W1 + (size_t)(h * 320) * H1_ + c;
    float a0 = 0.f, a1 = 0.f, a2 = 0.f, a3 = 0.f;
    #pragma unroll 4
    for (int r = 0; r < 320; r += 4) {
      a0 = fmaf(xp[r + 0], wp[(size_t)(r + 0) * H1_], a0);
      a1 = fmaf(xp[r + 1], wp[(size_t)(r + 1) * H1_], a1);
      a2 = fmaf(xp[r + 2], wp[(size_t)(r + 2) * H1_], a2);
      a3 = fmaf(xp[r + 3], wp[(size_t)(r + 3) * H1_], a3);
    }
    s_p[t] = (a0 + a1) + (a2 + a3);
  }
  __syncthreads();
  if (t < 128) {
    const int b  = t >> 3;
    const int ci = t & 7;
    const int c  = g * 8 + ci;
    x1w[b * H1_ + c] = fmaxf(s_p[t] + s_p[t + 128] + b1[c], 0.0f);
  }
  grid.sync();

  // ================= Phase C: FC2 + W3 =================
  for (int b = 0; b < BB; ++b)
    for (int d = t; d < H1_; d += NTH)
      sbuf[b * X1S + d] = x1w[b * H1_ + d];
  __syncthreads();
  {
    const int q  = t >> 6;           // row quarter 0..3 (rows q*128 .. +128)
    const int b  = lane >> 2;        // batch 0..15
    const int ci = lane & 3;
    const int c  = g * 4 + ci;       // output column
    const float* xp = sbuf + b * X1S + q * 128;
    const float* wp = W2 + (size_t)(q * 128) * H2_ + c;
    float a0 = 0.f, a1 = 0.f, a2 = 0.f, a3 = 0.f;
    #pragma unroll 4
    for (int r = 0; r < 128; r += 4) {
      a0 = fmaf(xp[r + 0], wp[(size_t)(r + 0) * H2_], a0);
      a1 = fmaf(xp[r + 1], wp[(size_t)(r + 1) * H2_], a1);
      a2 = fmaf(xp[r + 2], wp[(size_t)(r + 2) * H2_], a2);
      a3 = fmaf(xp[r + 3], wp[(size_t)(r + 3) * H2_], a3);
    }
    s_p[t] = (a0 + a1) + (a2 + a3);
  }
  __syncthreads();
  if (t < 64) {
    const int b  = t >> 2;
    const int ci = t & 3;
    const int c  = g * 4 + ci;
    float v = ((s_p[t] + s_p[t + 64]) + (s_p[t + 128] + s_p[t + 192])) + b2[c];
    v = fmaxf(v, 0.0f) * W3[c];
    // sum the 4 columns of this block for batch b (lanes ci=0..3 adjacent)
    v += __shfl_xor(v, 1);
    v += __shfl_xor(v, 2);
    if (ci == 0) pw[g * BB + b] = v;
  }
  grid.sync();

  // ================= Phase D =================
  if (g < BB && t < 64) {
    float v = pw[t * BB + g];
    v = wave_sum(v);
    if (t == 0) out[g] = v + b3[0];
  }
}

extern "C" void kernel_launch(void* const* d_in, const int* in_sizes, int n_in,
                              void* d_out, int out_size, void* d_ws, size_t ws_size,
                              hipStream_t stream) {
  const float* X     = (const float*)d_in[0];
  const int*   mpos  = (const int*)  d_in[6];
  const int*   mwt   = (const int*)  d_in[7];
  const int*   mmut  = (const int*)  d_in[8];
  const float* hid1  = (const float*)d_in[11];
  const float* hid2  = (const float*)d_in[12];
  const float* memb  = (const float*)d_in[13];
  const float* edges = (const float*)d_in[14];
  const float* Wse   = (const float*)d_in[15];
  const float* ln_g  = (const float*)d_in[16];
  const float* ln_b  = (const float*)d_in[17];
  const float* W1    = (const float*)d_in[18];
  const float* b1    = (const float*)d_in[19];
  const float* W2    = (const float*)d_in[20];
  const float* b2    = (const float*)d_in[21];
  const float* W3    = (const float*)d_in[22];
  const float* b3    = (const float*)d_in[23];

  float* ws  = (float*)d_ws;
  float* out = (float*)d_out;  // [16]

  void* kp[] = {
    (void*)&X, (void*)&mpos, (void*)&mwt, (void*)&mmut,
    (void*)&hid1, (void*)&hid2, (void*)&memb, (void*)&edges,
    (void*)&Wse, (void*)&ln_g, (void*)&ln_b,
    (void*)&W1, (void*)&b1, (void*)&W2, (void*)&b2, (void*)&W3, (void*)&b3,
    (void*)&ws, (void*)&out
  };
  hipLaunchCooperativeKernel((const void*)k_coop, dim3(NBLK), dim3(NTH),
                             kp, 0, stream);
}

// Round 10
// 57.902 us; speedup vs baseline: 1.3612x; 1.3612x over previous
//
#include <hip/hip_runtime.h>

// Problem constants (from the reference)
#define BB   16
#define LL   512
#define KNB  48
#define DIN_ 640
#define H1_  512
#define H2_  256
#define NBLK 64
#define NTH  256
#define X0S  641   // LDS stride for x0 (641 % 32 == 1 -> conflict-free)
#define X1S  516   // LDS stride for x1 (516 % 32 == 4 -> 2-way max, float4-aligned)

__device__ __forceinline__ float nz(float x) { return x == x ? x : 0.0f; }

__device__ __forceinline__ float wave_sum(float v) {
  #pragma unroll
  for (int m = 32; m >= 1; m >>= 1) v += __shfl_xor(v, m);
  return v;
}

// ---------------------------------------------------------------------------
// Single launch, 64 blocks x 256 threads, manual agent-scope handoffs.
//  A: EVERY block replicates embed+LN for ALL 16 batches (wave-per-batch,
//     in-wave ballot rank, no barriers).  ~56KB gathers/block, trivial.
//  FC1: block g owns cols [8g,8g+8) for all batches -> W1 read once
//     grid-wide (20KB/block, vs 1.25MB/CU in the 16-block kernel).
//  handoff #1 (release-add / acquire-spin on ws flag; 64 blks co-resident).
//  FC2: block g owns cols [4g,4g+4) + W3 partial dot -> pw[g][b].
//  handoff #2; blocks 0..15 reduce the 64 partials -> out[b].
// Flags are zeroed by a 64B hipMemsetAsync before the kernel each call.
// ---------------------------------------------------------------------------
__global__ __launch_bounds__(NTH) void k_fused(
    const float* __restrict__ X,      // [B,L,4,3]
    const int*   __restrict__ mpos,   // [B,2]
    const int*   __restrict__ mwt,    // [B,2]
    const int*   __restrict__ mmut,   // [B,2]
    const float* __restrict__ hid1,   // [B,L,128]
    const float* __restrict__ hid2,   // [B,L,128]
    const float* __restrict__ memb,   // [B,L,128]
    const float* __restrict__ edges,  // [B,L,48,128]
    const float* __restrict__ Wse,    // [21,128]
    const float* __restrict__ ln_g,   // [640]
    const float* __restrict__ ln_b,   // [640]
    const float* __restrict__ W1,     // [640,512]
    const float* __restrict__ b1,     // [512]
    const float* __restrict__ W2,     // [512,256]
    const float* __restrict__ b2,     // [256]
    const float* __restrict__ W3,     // [256,1]
    const float* __restrict__ b3,     // [1]
    float* __restrict__ ws,           // [flags(16) | pw 64*16 | x1w 16*512]
    float* __restrict__ out)          // [16]
{
  const int g    = blockIdx.x;
  const int t    = threadIdx.x;
  const int wv   = t >> 6;   // wave 0..3
  const int lane = t & 63;

  int*   flags = (int*)ws;            // [0]=fc1 done count, [1]=fc2 done count
  float* pw    = ws + 16;             // [64][16]
  float* x1w   = ws + 16 + NBLK * BB; // [16][512]

  __shared__ float x0s[BB * X0S];     // post-LN/ReLU x0, all batches
  __shared__ float x1s[BB * X1S];     // staged x1, all batches
  __shared__ float s_p[NTH];

  // ================= Phase A: replicated embed + LN (wave-per-batch) ======
  #pragma unroll
  for (int bi = 0; bi < 4; ++bi) {
    const int b = wv + bi * 4;
    const int p0 = mpos[b * 2], p1 = mpos[b * 2 + 1];
    const int m0 = mmut[b * 2], m1 = mmut[b * 2 + 1];
    const int w0 = mwt[b * 2],  w1 = mwt[b * 2 + 1];

    const float* a0p = X + (((size_t)(b * LL + p0)) * 4 + 1) * 3;
    const float* a1p = X + (((size_t)(b * LL + p1)) * 4 + 1) * 3;
    const float c0x = nz(a0p[0]), c0y = nz(a0p[1]), c0z = nz(a0p[2]);
    const float c1x = nz(a1p[0]), c1y = nz(a1p[1]), c1z = nz(a1p[2]);

    // rank of the other mutation (stable ties, == lax.top_k slot)
    const float dx = c0x - c1x, dy = c0y - c1y, dz = c0z - c1z;
    const float dq = sqrtf(dx * dx + dy * dy + dz * dz + 1e-6f);
    int cnt0 = 0, cnt1 = 0;
    #pragma unroll
    for (int k = 0; k < 8; ++k) {
      const int j = lane + k * 64;
      const float* a = X + (((size_t)(b * LL + j)) * 4 + 1) * 3;
      const float jx = nz(a[0]), jy = nz(a[1]), jz = nz(a[2]);
      const float e0x = jx - c0x, e0y = jy - c0y, e0z = jz - c0z;
      const float d0  = sqrtf(e0x * e0x + e0y * e0y + e0z * e0z + 1e-6f);
      const float e1x = jx - c1x, e1y = jy - c1y, e1z = jz - c1z;
      const float d1  = sqrtf(e1x * e1x + e1y * e1y + e1z * e1z + 1e-6f);
      cnt0 += __popcll(__ballot((d0 < dq) || (d0 == dq && j < p1)));
      cnt1 += __popcll(__ballot((d1 < dq) || (d1 == dq && j < p0)));
    }
    const int rk0 = cnt0, rk1 = cnt1;

    const int v0 = ((p0 + w0 + m0) != 0) ? 1 : 0;
    const int v1 = ((p1 + w1 + m1) != 0) ? 1 : 0;
    const float denom = fmaxf((float)(v0 + v1), 1.0f);

    // masked-mean embedding -> x0s[b]
    #pragma unroll
    for (int k = 0; k < 10; ++k) {
      const int d = lane + k * 64;
      float v = 0.0f;
      if (v0) {
        float e;
        if (d < 128)      e = hid1[(size_t)(b * LL + p0) * 128 + d];
        else if (d < 256) e = hid2[(size_t)(b * LL + p0) * 128 + (d - 128)];
        else if (d < 384) e = memb[(size_t)(b * LL + p0) * 128 + (d - 256)];
        else if (d < 512) e = Wse[m0 * 128 + (d - 384)];
        else              e = (rk0 < KNB)
                                ? edges[(((size_t)(b * LL + p0)) * KNB + rk0) * 128 + (d - 512)]
                                : 0.0f;
        v += e;
      }
      if (v1) {
        float e;
        if (d < 128)      e = hid1[(size_t)(b * LL + p1) * 128 + d];
        else if (d < 256) e = hid2[(size_t)(b * LL + p1) * 128 + (d - 128)];
        else if (d < 384) e = memb[(size_t)(b * LL + p1) * 128 + (d - 256)];
        else if (d < 512) e = Wse[m1 * 128 + (d - 384)];
        else              e = (rk1 < KNB)
                                ? edges[(((size_t)(b * LL + p1)) * KNB + rk1) * 128 + (d - 512)]
                                : 0.0f;
        v += e;
      }
      x0s[b * X0S + d] = v / denom;
    }

    // LayerNorm + ReLU (in-wave)
    float ps = 0.0f;
    #pragma unroll
    for (int k = 0; k < 10; ++k) ps += x0s[b * X0S + lane + k * 64];
    ps = wave_sum(ps);
    const float mu_ = ps / (float)DIN_;

    float pv = 0.0f;
    #pragma unroll
    for (int k = 0; k < 10; ++k) {
      const float z = x0s[b * X0S + lane + k * 64] - mu_;
      pv += z * z;
    }
    pv = wave_sum(pv);
    const float var = pv / (float)DIN_;
    const float inv = 1.0f / sqrtf(var + 1e-5f);

    #pragma unroll
    for (int k = 0; k < 10; ++k) {
      const int d = lane + k * 64;
      x0s[b * X0S + d] =
          fmaxf((x0s[b * X0S + d] - mu_) * inv * ln_g[d] + ln_b[d], 0.0f);
    }
  }
  __syncthreads();

  // ================= FC1: cols [8g, 8g+8) for all batches ================
  {
    const int c = t & 7, b = (t >> 3) & 15, h = t >> 7;
    const int col = g * 8 + c;
    const float* xp = x0s + b * X0S + h * 320;
    const float* wp = W1 + (size_t)(h * 320) * H1_ + col;
    float a0 = 0.f, a1 = 0.f, a2 = 0.f, a3 = 0.f;
    #pragma unroll 4
    for (int r = 0; r < 320; r += 4) {
      a0 = fmaf(xp[r + 0], wp[(size_t)(r + 0) * H1_], a0);
      a1 = fmaf(xp[r + 1], wp[(size_t)(r + 1) * H1_], a1);
      a2 = fmaf(xp[r + 2], wp[(size_t)(r + 2) * H1_], a2);
      a3 = fmaf(xp[r + 3], wp[(size_t)(r + 3) * H1_], a3);
    }
    s_p[t] = (a0 + a1) + (a2 + a3);
  }
  __syncthreads();
  if (t < 128) {
    const int c = t & 7, b = t >> 3;
    const int col = g * 8 + c;
    x1w[b * H1_ + col] = fmaxf(s_p[t] + s_p[t + 128] + b1[col], 0.0f);
  }
  // --------- handoff #1: x1 ready ---------
  __threadfence();
  __syncthreads();
  if (t == 0) {
    __hip_atomic_fetch_add(&flags[0], 1, __ATOMIC_RELEASE, __HIP_MEMORY_SCOPE_AGENT);
    while (__hip_atomic_load(&flags[0], __ATOMIC_ACQUIRE, __HIP_MEMORY_SCOPE_AGENT) < NBLK)
      __builtin_amdgcn_s_sleep(2);
  }
  __syncthreads();
  __threadfence();

  // ================= FC2: stage x1, cols [4g, 4g+4) =====================
  for (int i = t; i < BB * H1_ / 4; i += NTH) {   // 2048 float4s
    const int b  = i >> 7;
    const int dd = (i & 127) << 2;
    const float4 v = reinterpret_cast<const float4*>(x1w)[i];
    *reinterpret_cast<float4*>(&x1s[b * X1S + dd]) = v;
  }
  __syncthreads();
  {
    const int c = t & 3, b = (t >> 2) & 15, q = t >> 6;
    const int col = g * 4 + c;
    const float* xp = x1s + b * X1S + q * 128;
    const float* wp = W2 + (size_t)(q * 128) * H2_ + col;
    float a0 = 0.f, a1 = 0.f, a2 = 0.f, a3 = 0.f;
    #pragma unroll 4
    for (int r = 0; r < 128; r += 4) {
      a0 = fmaf(xp[r + 0], wp[(size_t)(r + 0) * H2_], a0);
      a1 = fmaf(xp[r + 1], wp[(size_t)(r + 1) * H2_], a1);
      a2 = fmaf(xp[r + 2], wp[(size_t)(r + 2) * H2_], a2);
      a3 = fmaf(xp[r + 3], wp[(size_t)(r + 3) * H2_], a3);
    }
    s_p[t] = (a0 + a1) + (a2 + a3);
  }
  __syncthreads();
  if (t < 64) {
    const int c = t & 3, b = t >> 2;
    const int col = g * 4 + c;
    float v = ((s_p[t] + s_p[t + 64]) + (s_p[t + 128] + s_p[t + 192])) + b2[col];
    v = fmaxf(v, 0.0f) * W3[col];
    v += __shfl_xor(v, 1);
    v += __shfl_xor(v, 2);
    if (c == 0) pw[g * BB + b] = v;
  }
  // --------- handoff #2: partials ready ---------
  __threadfence();
  __syncthreads();
  if (t == 0)
    __hip_atomic_fetch_add(&flags[1], 1, __ATOMIC_RELEASE, __HIP_MEMORY_SCOPE_AGENT);

  // ================= final reduce (blocks 0..15) =========================
  if (g < BB) {
    if (t == 0) {
      while (__hip_atomic_load(&flags[1], __ATOMIC_ACQUIRE, __HIP_MEMORY_SCOPE_AGENT) < NBLK)
        __builtin_amdgcn_s_sleep(2);
    }
    __syncthreads();
    __threadfence();
    if (t < 64) {
      float v = pw[t * BB + g];
      v = wave_sum(v);
      if (t == 0) out[g] = v + b3[0];
    }
  }
}

extern "C" void kernel_launch(void* const* d_in, const int* in_sizes, int n_in,
                              void* d_out, int out_size, void* d_ws, size_t ws_size,
                              hipStream_t stream) {
  const float* X     = (const float*)d_in[0];
  const int*   mpos  = (const int*)  d_in[6];
  const int*   mwt   = (const int*)  d_in[7];
  const int*   mmut  = (const int*)  d_in[8];
  const float* hid1  = (const float*)d_in[11];
  const float* hid2  = (const float*)d_in[12];
  const float* memb  = (const float*)d_in[13];
  const float* edges = (const float*)d_in[14];
  const float* Wse   = (const float*)d_in[15];
  const float* ln_g  = (const float*)d_in[16];
  const float* ln_b  = (const float*)d_in[17];
  const float* W1    = (const float*)d_in[18];
  const float* b1    = (const float*)d_in[19];
  const float* W2    = (const float*)d_in[20];
  const float* b2    = (const float*)d_in[21];
  const float* W3    = (const float*)d_in[22];
  const float* b3    = (const float*)d_in[23];

  float* ws  = (float*)d_ws;
  float* out = (float*)d_out;  // [16]

  // zero the handoff flags (graph-capturable stream op)
  hipMemsetAsync(d_ws, 0, 64, stream);

  k_fused<<<NBLK, NTH, 0, stream>>>(X, mpos, mwt, mmut, hid1, hid2, memb,
                                    edges, Wse, ln_g, ln_b, W1, b1, W2, b2,
                                    W3, b3, ws, out);
}

// Round 11
// 35.410 us; speedup vs baseline: 2.2258x; 1.6352x over previous
//
#include <hip/hip_runtime.h>

// Problem constants (from the reference)
#define BB   16
#define LL   512
#define KNB  48
#define DIN_ 640
#define H1_  512
#define H2_  256
#define X0S  641   // LDS stride for x0 (641 % 32 == 1 -> conflict-free broadcast)

__device__ __forceinline__ float nz(float x) { return x == x ? x : 0.0f; }

__device__ __forceinline__ float wave_sum(float v) {
  #pragma unroll
  for (int m = 32; m >= 1; m >>= 1) v += __shfl_xor(v, m);
  return v;
}

// ---------------------------------------------------------------------------
// K1 (64 blocks x 256 thr): replicated embed+LN for ALL batches (wave-per-
// batch, in-wave ballot rank -- exact lax.top_k stable-tie semantics), then
// FC1 cols [8g, 8g+8) for all 16 batches.  W1 is read once across the grid
// (20KB/block) instead of 1.25MB per CU.  x1 -> ws (every element written
// every call; no stale-ws hazard).
// ---------------------------------------------------------------------------
__global__ __launch_bounds__(256) void k_front(
    const float* __restrict__ X,      // [B,L,4,3]
    const int*   __restrict__ mpos,   // [B,2]
    const int*   __restrict__ mwt,    // [B,2]
    const int*   __restrict__ mmut,   // [B,2]
    const float* __restrict__ hid1,   // [B,L,128]
    const float* __restrict__ hid2,   // [B,L,128]
    const float* __restrict__ memb,   // [B,L,128]
    const float* __restrict__ edges,  // [B,L,48,128]
    const float* __restrict__ Wse,    // [21,128]
    const float* __restrict__ ln_g,   // [640]
    const float* __restrict__ ln_b,   // [640]
    const float* __restrict__ W1,     // [640,512]
    const float* __restrict__ b1,     // [512]
    float* __restrict__ x1w)          // [16,512] post-ReLU FC1 out
{
  const int g    = blockIdx.x;   // 0..63
  const int t    = threadIdx.x;
  const int wv   = t >> 6;       // wave 0..3
  const int lane = t & 63;

  __shared__ float x0s[BB * X0S];
  __shared__ float s_p[256];

  // ===== Phase A: replicated embed + LN (wave-per-batch) =====
  #pragma unroll
  for (int bi = 0; bi < 4; ++bi) {
    const int b = wv + bi * 4;
    const int p0 = mpos[b * 2], p1 = mpos[b * 2 + 1];
    const int m0 = mmut[b * 2], m1 = mmut[b * 2 + 1];
    const int w0 = mwt[b * 2],  w1 = mwt[b * 2 + 1];

    const float* a0p = X + (((size_t)(b * LL + p0)) * 4 + 1) * 3;
    const float* a1p = X + (((size_t)(b * LL + p1)) * 4 + 1) * 3;
    const float c0x = nz(a0p[0]), c0y = nz(a0p[1]), c0z = nz(a0p[2]);
    const float c1x = nz(a1p[0]), c1y = nz(a1p[1]), c1z = nz(a1p[2]);

    // rank of the other mutation (stable ties == lax.top_k slot)
    const float dx = c0x - c1x, dy = c0y - c1y, dz = c0z - c1z;
    const float dq = sqrtf(dx * dx + dy * dy + dz * dz + 1e-6f);
    int cnt0 = 0, cnt1 = 0;
    #pragma unroll
    for (int k = 0; k < 8; ++k) {
      const int j = lane + k * 64;
      const float* a = X + (((size_t)(b * LL + j)) * 4 + 1) * 3;
      const float jx = nz(a[0]), jy = nz(a[1]), jz = nz(a[2]);
      const float e0x = jx - c0x, e0y = jy - c0y, e0z = jz - c0z;
      const float d0  = sqrtf(e0x * e0x + e0y * e0y + e0z * e0z + 1e-6f);
      const float e1x = jx - c1x, e1y = jy - c1y, e1z = jz - c1z;
      const float d1  = sqrtf(e1x * e1x + e1y * e1y + e1z * e1z + 1e-6f);
      cnt0 += __popcll(__ballot((d0 < dq) || (d0 == dq && j < p1)));
      cnt1 += __popcll(__ballot((d1 < dq) || (d1 == dq && j < p0)));
    }
    const int rk0 = cnt0, rk1 = cnt1;

    const int v0 = ((p0 + w0 + m0) != 0) ? 1 : 0;
    const int v1 = ((p1 + w1 + m1) != 0) ? 1 : 0;
    const float denom = fmaxf((float)(v0 + v1), 1.0f);

    #pragma unroll
    for (int k = 0; k < 10; ++k) {
      const int d = lane + k * 64;
      float v = 0.0f;
      if (v0) {
        float e;
        if (d < 128)      e = hid1[(size_t)(b * LL + p0) * 128 + d];
        else if (d < 256) e = hid2[(size_t)(b * LL + p0) * 128 + (d - 128)];
        else if (d < 384) e = memb[(size_t)(b * LL + p0) * 128 + (d - 256)];
        else if (d < 512) e = Wse[m0 * 128 + (d - 384)];
        else              e = (rk0 < KNB)
                                ? edges[(((size_t)(b * LL + p0)) * KNB + rk0) * 128 + (d - 512)]
                                : 0.0f;
        v += e;
      }
      if (v1) {
        float e;
        if (d < 128)      e = hid1[(size_t)(b * LL + p1) * 128 + d];
        else if (d < 256) e = hid2[(size_t)(b * LL + p1) * 128 + (d - 128)];
        else if (d < 384) e = memb[(size_t)(b * LL + p1) * 128 + (d - 256)];
        else if (d < 512) e = Wse[m1 * 128 + (d - 384)];
        else              e = (rk1 < KNB)
                                ? edges[(((size_t)(b * LL + p1)) * KNB + rk1) * 128 + (d - 512)]
                                : 0.0f;
        v += e;
      }
      x0s[b * X0S + d] = v / denom;
    }

    // LayerNorm + ReLU (in-wave)
    float ps = 0.0f;
    #pragma unroll
    for (int k = 0; k < 10; ++k) ps += x0s[b * X0S + lane + k * 64];
    ps = wave_sum(ps);
    const float mu_ = ps / (float)DIN_;

    float pv = 0.0f;
    #pragma unroll
    for (int k = 0; k < 10; ++k) {
      const float z = x0s[b * X0S + lane + k * 64] - mu_;
      pv += z * z;
    }
    pv = wave_sum(pv);
    const float inv = 1.0f / sqrtf(pv / (float)DIN_ + 1e-5f);

    #pragma unroll
    for (int k = 0; k < 10; ++k) {
      const int d = lane + k * 64;
      x0s[b * X0S + d] =
          fmaxf((x0s[b * X0S + d] - mu_) * inv * ln_g[d] + ln_b[d], 0.0f);
    }
  }
  __syncthreads();

  // ===== FC1: cols [8g, 8g+8) for all 16 batches =====
  {
    const int c = t & 7, b = (t >> 3) & 15, h = t >> 7;
    const int col = g * 8 + c;
    const float* xp = x0s + b * X0S + h * 320;
    const float* wp = W1 + (size_t)(h * 320) * H1_ + col;
    float a0 = 0.f, a1 = 0.f, a2 = 0.f, a3 = 0.f;
    #pragma unroll 4
    for (int r = 0; r < 320; r += 4) {
      a0 = fmaf(xp[r + 0], wp[(size_t)(r + 0) * H1_], a0);
      a1 = fmaf(xp[r + 1], wp[(size_t)(r + 1) * H1_], a1);
      a2 = fmaf(xp[r + 2], wp[(size_t)(r + 2) * H1_], a2);
      a3 = fmaf(xp[r + 3], wp[(size_t)(r + 3) * H1_], a3);
    }
    s_p[t] = (a0 + a1) + (a2 + a3);
  }
  __syncthreads();
  if (t < 128) {
    const int c = t & 7, b = t >> 3;
    const int col = g * 8 + c;
    x1w[b * H1_ + col] = fmaxf(s_p[t] + s_p[t + 128] + b1[col], 0.0f);
  }
}

// ---------------------------------------------------------------------------
// K2 (16 blocks x 512 thr): block b = batch b.  FC2 512->256 (W2 0.5MB/CU,
// down from 1.75MB in the fused kernel) + W3 dot + in-block reduce -> out[b].
// Layout: wave sl (0..7) owns a 64-row slice; lanes own float4 col-groups ->
// each W2 load is 1KB contiguous per wave; x1 reads are wave-uniform LDS
// broadcasts.
// ---------------------------------------------------------------------------
__global__ __launch_bounds__(512) void k_back(
    const float* __restrict__ x1w,  // [16,512]
    const float* __restrict__ W2,   // [512,256]
    const float* __restrict__ b2,   // [256]
    const float* __restrict__ W3,   // [256,1]
    const float* __restrict__ b3,   // [1]
    float* __restrict__ out)        // [16]
{
  const int b = blockIdx.x;
  const int t = threadIdx.x;

  __shared__ float x1s[H1_];
  __shared__ float s_fc[8 * H2_];   // per-slice partials
  __shared__ float s_w[4];

  if (t < 128)
    reinterpret_cast<float4*>(x1s)[t] =
        reinterpret_cast<const float4*>(x1w + (size_t)b * H1_)[t];
  __syncthreads();

  {
    const int gg = t & 63;          // float4 col-group 0..63
    const int sl = t >> 6;          // row slice 0..7 (64 rows)
    const float* xp = x1s + sl * 64;
    const float* wp = W2 + (size_t)(sl * 64) * H2_;
    float4 a = make_float4(0.f, 0.f, 0.f, 0.f);
    #pragma unroll 8
    for (int r = 0; r < 64; ++r) {
      const float xv = xp[r];       // wave-uniform broadcast
      const float4 w = reinterpret_cast<const float4*>(wp + (size_t)r * H2_)[gg];
      a.x = fmaf(xv, w.x, a.x);
      a.y = fmaf(xv, w.y, a.y);
      a.z = fmaf(xv, w.z, a.z);
      a.w = fmaf(xv, w.w, a.w);
    }
    reinterpret_cast<float4*>(s_fc)[sl * 64 + gg] = a;
  }
  __syncthreads();

  float contrib = 0.0f;
  if (t < H2_) {
    float acc = 0.0f;
    #pragma unroll
    for (int sl = 0; sl < 8; ++sl) acc += s_fc[sl * H2_ + t];
    contrib = fmaxf(acc + b2[t], 0.0f) * W3[t];
  }
  contrib = wave_sum(contrib);
  if (t < H2_ && (t & 63) == 0) s_w[t >> 6] = contrib;
  __syncthreads();
  if (t == 0) out[b] = (s_w[0] + s_w[1]) + (s_w[2] + s_w[3]) + b3[0];
}

extern "C" void kernel_launch(void* const* d_in, const int* in_sizes, int n_in,
                              void* d_out, int out_size, void* d_ws, size_t ws_size,
                              hipStream_t stream) {
  const float* X     = (const float*)d_in[0];
  const int*   mpos  = (const int*)  d_in[6];
  const int*   mwt   = (const int*)  d_in[7];
  const int*   mmut  = (const int*)  d_in[8];
  const float* hid1  = (const float*)d_in[11];
  const float* hid2  = (const float*)d_in[12];
  const float* memb  = (const float*)d_in[13];
  const float* edges = (const float*)d_in[14];
  const float* Wse   = (const float*)d_in[15];
  const float* ln_g  = (const float*)d_in[16];
  const float* ln_b  = (const float*)d_in[17];
  const float* W1    = (const float*)d_in[18];
  const float* b1    = (const float*)d_in[19];
  const float* W2    = (const float*)d_in[20];
  const float* b2    = (const float*)d_in[21];
  const float* W3    = (const float*)d_in[22];
  const float* b3    = (const float*)d_in[23];

  float* x1w = (float*)d_ws;   // [16,512]
  float* out = (float*)d_out;  // [16]

  k_front<<<64, 256, 0, stream>>>(X, mpos, mwt, mmut, hid1, hid2, memb, edges,
                                  Wse, ln_g, ln_b, W1, b1, x1w);
  k_back<<<16, 512, 0, stream>>>(x1w, W2, b2, W3, b3, out);
}

// Round 12
// 21.155 us; speedup vs baseline: 3.7255x; 1.6738x over previous
//
#include <hip/hip_runtime.h>

// Problem constants (from the reference)
#define BB   16
#define LL   512
#define KNB  48
#define DIN_ 640
#define H1_  512
#define H2_  256
#define NT   1024  // 16 waves/block

__device__ __forceinline__ float nz(float x) { return x == x ? x : 0.0f; }

__device__ __forceinline__ float wave_sum(float v) {
  #pragma unroll
  for (int m = 32; m >= 1; m >>= 1) v += __shfl_xor(v, m);
  return v;
}

// ---------------------------------------------------------------------------
// One block per batch element, fully fused (R8 structure) + ReLU-sparsity
// row skipping in both FC layers:
//   - x0/x1 are post-ReLU -> ~50% exact zeros.  fmaf(0,w,acc)==acc exactly,
//     so rows with zero activation never need their W1/W2 row loaded.
//   - compact nonzero row indices via ballot/popcount prefix (wave-uniform
//     skip; deterministic).  Cuts the ~1.75MB/CU weight stream roughly in
//     half -- that stream is the measured kernel wall (R6~R8 neutrality).
// ---------------------------------------------------------------------------
__global__ __launch_bounds__(NT) void k_fused(
    const float* __restrict__ X,      // [B,L,4,3]
    const int*   __restrict__ mpos,   // [B,2]
    const int*   __restrict__ mwt,    // [B,2]
    const int*   __restrict__ mmut,   // [B,2]
    const float* __restrict__ hid1,   // [B,L,128]
    const float* __restrict__ hid2,   // [B,L,128]
    const float* __restrict__ memb,   // [B,L,128]
    const float* __restrict__ edges,  // [B,L,48,128]
    const float* __restrict__ Wse,    // [21,128]
    const float* __restrict__ ln_g,   // [640]
    const float* __restrict__ ln_b,   // [640]
    const float* __restrict__ W1,     // [640,512]
    const float* __restrict__ b1,     // [512]
    const float* __restrict__ W2,     // [512,256]
    const float* __restrict__ b2,     // [256]
    const float* __restrict__ W3,     // [256,1]
    const float* __restrict__ b3,     // [1]
    float* __restrict__ out)          // [16]
{
  const int b    = blockIdx.x;
  const int t    = threadIdx.x;
  const int wid  = t >> 6;           // wave id 0..15
  const int lane = t & 63;

  __shared__ float s_x0[DIN_];       // embedding -> post-LN/ReLU (in place)
  __shared__ float s_x1[H1_];        // post-ReLU FC1 output
  __shared__ float s_fc[4096];       // FC partials
  __shared__ float s_w[48];          // LN sums / final partials
  __shared__ int   s_cnt[32];        // ballot counts (rank + compaction)
  __shared__ int   s_idx0[DIN_];     // compacted nonzero rows of x0
  __shared__ int   s_idx1[H1_];      // compacted nonzero rows of x1

  const int p[2]  = { mpos[b * 2 + 0], mpos[b * 2 + 1] };
  const int mu[2] = { mmut[b * 2 + 0], mmut[b * 2 + 1] };
  const int wt[2] = { mwt[b * 2 + 0],  mwt[b * 2 + 1]  };

  float3 ca[2];
  #pragma unroll
  for (int m = 0; m < 2; ++m) {
    const float* a = X + (((size_t)(b * LL + p[m])) * 4 + 1) * 3;
    ca[m] = make_float3(nz(a[0]), nz(a[1]), nz(a[2]));
  }

  // ---- phase 1: ranks via ballot/popcount (stable ties == lax.top_k) ----
  {
    bool pr0 = false, pr1 = false;
    if (t < LL) {
      const float* a = X + (((size_t)(b * LL + t)) * 4 + 1) * 3;
      const float jx = nz(a[0]), jy = nz(a[1]), jz = nz(a[2]);
      const float dx = ca[0].x - ca[1].x, dy = ca[0].y - ca[1].y, dz = ca[0].z - ca[1].z;
      const float dq = sqrtf(dx * dx + dy * dy + dz * dz + 1e-6f);

      const float e0x = jx - ca[0].x, e0y = jy - ca[0].y, e0z = jz - ca[0].z;
      const float d0  = sqrtf(e0x * e0x + e0y * e0y + e0z * e0z + 1e-6f);
      const float e1x = jx - ca[1].x, e1y = jy - ca[1].y, e1z = jz - ca[1].z;
      const float d1  = sqrtf(e1x * e1x + e1y * e1y + e1z * e1z + 1e-6f);

      pr0 = (d0 < dq) || (d0 == dq && t < p[1]);
      pr1 = (d1 < dq) || (d1 == dq && t < p[0]);
    }
    const unsigned long long m0 = __ballot(pr0);
    const unsigned long long m1 = __ballot(pr1);
    if (lane == 0) {
      s_cnt[wid]      = __popcll(m0);
      s_cnt[16 + wid] = __popcll(m1);
    }
  }
  __syncthreads();

  int rk[2] = { 0, 0 };
  #pragma unroll
  for (int w = 0; w < 16; ++w) { rk[0] += s_cnt[w]; rk[1] += s_cnt[16 + w]; }

  const int v0 = ((p[0] + wt[0] + mu[0]) != 0) ? 1 : 0;
  const int v1 = ((p[1] + wt[1] + mu[1]) != 0) ? 1 : 0;
  const float denom = fmaxf((float)(v0 + v1), 1.0f);
  const int vv[2] = { v0, v1 };

  // ---- phase 2: masked-mean embedding -> s_x0 ----
  if (t < DIN_) {
    const int d = t;
    float v = 0.0f;
    #pragma unroll
    for (int m = 0; m < 2; ++m) {
      if (!vv[m]) continue;
      const int base = p[m];
      float e;
      if (d < 128)      e = hid1[(size_t)(b * LL + base) * 128 + d];
      else if (d < 256) e = hid2[(size_t)(b * LL + base) * 128 + (d - 128)];
      else if (d < 384) e = memb[(size_t)(b * LL + base) * 128 + (d - 256)];
      else if (d < 512) e = Wse[mu[m] * 128 + (d - 384)];
      else              e = (rk[m] < KNB)
                              ? edges[(((size_t)(b * LL + base)) * KNB + rk[m]) * 128 + (d - 512)]
                              : 0.0f;
      v += e;
    }
    s_x0[d] = v / denom;
  }
  __syncthreads();

  // ---- phase 3: LayerNorm (shuffle reductions) + ReLU in place ----
  float ps = (t < DIN_) ? s_x0[t] : 0.0f;
  ps = wave_sum(ps);
  if (lane == 0) s_w[wid] = ps;
  __syncthreads();
  float mu_ = 0.0f;
  #pragma unroll
  for (int w = 0; w < 16; ++w) mu_ += s_w[w];
  mu_ /= (float)DIN_;

  float pv = 0.0f;
  if (t < DIN_) { const float z = s_x0[t] - mu_; pv = z * z; }
  pv = wave_sum(pv);
  if (lane == 0) s_w[16 + wid] = pv;
  __syncthreads();
  float var = 0.0f;
  #pragma unroll
  for (int w = 0; w < 16; ++w) var += s_w[16 + w];
  var /= (float)DIN_;
  const float inv = 1.0f / sqrtf(var + 1e-5f);

  if (t < DIN_)
    s_x0[t] = fmaxf((s_x0[t] - mu_) * inv * ln_g[t] + ln_b[t], 0.0f);
  __syncthreads();

  // ---- compact nonzero rows of x0 ----
  int nnz0;
  {
    const bool pred = (t < DIN_) && (s_x0[t < DIN_ ? t : 0] > 0.0f);
    const unsigned long long mk = __ballot(pred);
    const int rank = __popcll(mk & ((1ULL << lane) - 1ULL));
    if (lane == 0) s_cnt[wid] = (t < DIN_) ? __popcll(mk) : 0;
    __syncthreads();
    int woff = 0;
    for (int w = 0; w < wid; ++w) woff += s_cnt[w];
    nnz0 = 0;
    #pragma unroll
    for (int w = 0; w < 10; ++w) nnz0 += s_cnt[w];
    if (pred) s_idx0[woff + rank] = t;
  }
  __syncthreads();

  // ---- phase 4: FC1 640->512 over nonzero rows only ----
  {
    const int fg = t & 127;          // float4 col-group (4 cols)
    const int sl = t >> 7;           // slice 0..7 of the compacted list
    const int chunk = (nnz0 + 7) >> 3;
    const int i0 = sl * chunk;
    const int i1 = min(i0 + chunk, nnz0);
    float4 a = make_float4(0.f, 0.f, 0.f, 0.f);
    for (int i = i0; i < i1; ++i) {
      const int r = s_idx0[i];                        // wave-uniform
      const float xv = s_x0[r];                       // broadcast
      const float4 w = reinterpret_cast<const float4*>(W1 + (size_t)r * H1_)[fg];
      a.x = fmaf(xv, w.x, a.x);
      a.y = fmaf(xv, w.y, a.y);
      a.z = fmaf(xv, w.z, a.z);
      a.w = fmaf(xv, w.w, a.w);
    }
    reinterpret_cast<float4*>(s_fc)[sl * 128 + fg] = a;
  }
  __syncthreads();
  if (t < H1_) {
    float acc = 0.0f;
    #pragma unroll
    for (int sl = 0; sl < 8; ++sl) acc += s_fc[sl * 512 + t];
    s_x1[t] = fmaxf(acc + b1[t], 0.0f);
  }
  __syncthreads();

  // ---- compact nonzero rows of x1 ----
  int nnz1;
  {
    const bool pred = (t < H1_) && (s_x1[t < H1_ ? t : 0] > 0.0f);
    const unsigned long long mk = __ballot(pred);
    const int rank = __popcll(mk & ((1ULL << lane) - 1ULL));
    if (lane == 0) s_cnt[wid] = (t < H1_) ? __popcll(mk) : 0;
    __syncthreads();
    int woff = 0;
    for (int w = 0; w < wid; ++w) woff += s_cnt[w];
    nnz1 = 0;
    #pragma unroll
    for (int w = 0; w < 8; ++w) nnz1 += s_cnt[w];
    if (pred) s_idx1[woff + rank] = t;
  }
  __syncthreads();

  // ---- phase 5: FC2 512->256 over nonzero rows + W3 dot ----
  {
    const int fg = t & 63;           // float4 col-group (4 cols)
    const int sl = t >> 6;           // slice 0..15 == wid
    const int chunk = (nnz1 + 15) >> 4;
    const int i0 = sl * chunk;
    const int i1 = min(i0 + chunk, nnz1);
    float4 a = make_float4(0.f, 0.f, 0.f, 0.f);
    for (int i = i0; i < i1; ++i) {
      const int r = s_idx1[i];
      const float xv = s_x1[r];
      const float4 w = reinterpret_cast<const float4*>(W2 + (size_t)r * H2_)[fg];
      a.x = fmaf(xv, w.x, a.x);
      a.y = fmaf(xv, w.y, a.y);
      a.z = fmaf(xv, w.z, a.z);
      a.w = fmaf(xv, w.w, a.w);
    }
    reinterpret_cast<float4*>(s_fc)[sl * 64 + fg] = a;
  }
  __syncthreads();

  float contrib = 0.0f;
  if (t < H2_) {
    float acc = 0.0f;
    #pragma unroll
    for (int sl = 0; sl < 16; ++sl) acc += s_fc[sl * 256 + t];
    contrib = fmaxf(acc + b2[t], 0.0f) * W3[t];
  }
  contrib = wave_sum(contrib);
  if (lane == 0 && wid < 4) s_w[32 + wid] = contrib;
  __syncthreads();
  if (t == 0)
    out[b] = ((s_w[32] + s_w[33]) + (s_w[34] + s_w[35])) + b3[0];
}

extern "C" void kernel_launch(void* const* d_in, const int* in_sizes, int n_in,
                              void* d_out, int out_size, void* d_ws, size_t ws_size,
                              hipStream_t stream) {
  const float* X     = (const float*)d_in[0];
  const int*   mpos  = (const int*)  d_in[6];
  const int*   mwt   = (const int*)  d_in[7];
  const int*   mmut  = (const int*)  d_in[8];
  const float* hid1  = (const float*)d_in[11];
  const float* hid2  = (const float*)d_in[12];
  const float* memb  = (const float*)d_in[13];
  const float* edges = (const float*)d_in[14];
  const float* Wse   = (const float*)d_in[15];
  const float* ln_g  = (const float*)d_in[16];
  const float* ln_b  = (const float*)d_in[17];
  const float* W1    = (const float*)d_in[18];
  const float* b1    = (const float*)d_in[19];
  const float* W2    = (const float*)d_in[20];
  const float* b2    = (const float*)d_in[21];
  const float* W3    = (const float*)d_in[22];
  const float* b3    = (const float*)d_in[23];

  float* out = (float*)d_out;  // [16]

  k_fused<<<BB, NT, 0, stream>>>(X, mpos, mwt, mmut, hid1, hid2, memb, edges,
                                 Wse, ln_g, ln_b, W1, b1, W2, b2, W3, b3, out);
}

// Round 14
// 21.026 us; speedup vs baseline: 3.7484x; 1.0061x over previous
//
#include <hip/hip_runtime.h>

// Problem constants (from the reference)
#define BB   16
#define LL   512
#define KNB  48
#define DIN_ 640
#define H1_  512
#define H2_  256
#define NT   1024  // 16 waves/block

__device__ __forceinline__ float nz(float x) { return x == x ? x : 0.0f; }

__device__ __forceinline__ float wave_sum(float v) {
  #pragma unroll
  for (int m = 32; m >= 1; m >>= 1) v += __shfl_xor(v, m);
  return v;
}

// ---------------------------------------------------------------------------
// One block per batch element, fully fused, phase-compressed (10 barriers):
//   - rank predicate + d<512 embedding gathers issued together (independent
//     loads overlap); only the 128 edge dims wait on the rank.
//   - single-pass LayerNorm (var = E[x^2] - mu^2).
//   - ReLU-sparsity row skipping in FC1/FC2 (fmaf(0,w,a)==a exactly);
//     compaction ballots fused into the ReLU-write regions.
// ---------------------------------------------------------------------------
__global__ __launch_bounds__(NT) void k_fused(
    const float* __restrict__ X,      // [B,L,4,3]
    const int*   __restrict__ mpos,   // [B,2]
    const int*   __restrict__ mwt,    // [B,2]
    const int*   __restrict__ mmut,   // [B,2]
    const float* __restrict__ hid1,   // [B,L,128]
    const float* __restrict__ hid2,   // [B,L,128]
    const float* __restrict__ memb,   // [B,L,128]
    const float* __restrict__ edges,  // [B,L,48,128]
    const float* __restrict__ Wse,    // [21,128]
    const float* __restrict__ ln_g,   // [640]
    const float* __restrict__ ln_b,   // [640]
    const float* __restrict__ W1,     // [640,512]
    const float* __restrict__ b1,     // [512]
    const float* __restrict__ W2,     // [512,256]
    const float* __restrict__ b2,     // [256]
    const float* __restrict__ W3,     // [256,1]
    const float* __restrict__ b3,     // [1]
    float* __restrict__ out)          // [16]
{
  const int b    = blockIdx.x;
  const int t    = threadIdx.x;
  const int wid  = t >> 6;           // wave id 0..15
  const int lane = t & 63;

  __shared__ float s_x0[DIN_];
  __shared__ float s_x1[H1_];
  __shared__ float s_fc[4096];
  __shared__ float s_w[48];
  __shared__ int   s_cnt[32];
  __shared__ int   s_idx0[DIN_];
  __shared__ int   s_idx1[H1_];

  const int p0 = mpos[b * 2], p1 = mpos[b * 2 + 1];
  const int m0 = mmut[b * 2], m1 = mmut[b * 2 + 1];
  const int w0 = mwt[b * 2],  w1 = mwt[b * 2 + 1];

  const float* a0p = X + (((size_t)(b * LL + p0)) * 4 + 1) * 3;
  const float* a1p = X + (((size_t)(b * LL + p1)) * 4 + 1) * 3;
  const float c0x = nz(a0p[0]), c0y = nz(a0p[1]), c0z = nz(a0p[2]);
  const float c1x = nz(a1p[0]), c1y = nz(a1p[1]), c1z = nz(a1p[2]);

  const int v0 = ((p0 + w0 + m0) != 0) ? 1 : 0;
  const int v1 = ((p1 + w1 + m1) != 0) ? 1 : 0;
  const float denom = fmaxf((float)(v0 + v1), 1.0f);

  // ---- merged phase: rank predicate + embed(d<512) ----
  bool pr0 = false, pr1 = false;
  if (t < LL) {
    const float* a = X + (((size_t)(b * LL + t)) * 4 + 1) * 3;
    const float jx = nz(a[0]), jy = nz(a[1]), jz = nz(a[2]);
    const float dx = c0x - c1x, dy = c0y - c1y, dz = c0z - c1z;
    const float dq = sqrtf(dx * dx + dy * dy + dz * dz + 1e-6f);

    const float e0x = jx - c0x, e0y = jy - c0y, e0z = jz - c0z;
    const float d0  = sqrtf(e0x * e0x + e0y * e0y + e0z * e0z + 1e-6f);
    const float e1x = jx - c1x, e1y = jy - c1y, e1z = jz - c1z;
    const float d1  = sqrtf(e1x * e1x + e1y * e1y + e1z * e1z + 1e-6f);

    pr0 = (d0 < dq) || (d0 == dq && t < p1);
    pr1 = (d1 < dq) || (d1 == dq && t < p0);
  }
  {
    const unsigned long long mk0 = __ballot(pr0);
    const unsigned long long mk1 = __ballot(pr1);
    if (lane == 0) {
      s_cnt[wid]      = (int)__popcll(mk0);
      s_cnt[16 + wid] = (int)__popcll(mk1);
    }
  }
  if (t < 512) {
    const int d = t;
    float v = 0.0f;
    if (v0) {
      float e;
      if (d < 128)      e = hid1[(size_t)(b * LL + p0) * 128 + d];
      else if (d < 256) e = hid2[(size_t)(b * LL + p0) * 128 + (d - 128)];
      else if (d < 384) e = memb[(size_t)(b * LL + p0) * 128 + (d - 256)];
      else              e = Wse[m0 * 128 + (d - 384)];
      v += e;
    }
    if (v1) {
      float e;
      if (d < 128)      e = hid1[(size_t)(b * LL + p1) * 128 + d];
      else if (d < 256) e = hid2[(size_t)(b * LL + p1) * 128 + (d - 128)];
      else if (d < 384) e = memb[(size_t)(b * LL + p1) * 128 + (d - 256)];
      else              e = Wse[m1 * 128 + (d - 384)];
      v += e;
    }
    s_x0[d] = v / denom;
  }
  __syncthreads();  // B1: s_cnt ready

  int rk0 = 0, rk1 = 0;
  #pragma unroll
  for (int w = 0; w < 16; ++w) { rk0 += s_cnt[w]; rk1 += s_cnt[16 + w]; }

  if (t >= 512 && t < DIN_) {
    const int d = t;
    float v = 0.0f;
    if (v0) {
      v += (rk0 < KNB)
             ? edges[(((size_t)(b * LL + p0)) * KNB + rk0) * 128 + (d - 512)]
             : 0.0f;
    }
    if (v1) {
      v += (rk1 < KNB)
             ? edges[(((size_t)(b * LL + p1)) * KNB + rk1) * 128 + (d - 512)]
             : 0.0f;
    }
    s_x0[d] = v / denom;
  }
  __syncthreads();  // B2: x0 complete

  // ---- single-pass LayerNorm ----
  float xs = 0.0f, xq = 0.0f;
  if (t < DIN_) { const float x = s_x0[t]; xs = x; xq = x * x; }
  xs = wave_sum(xs);
  xq = wave_sum(xq);
  if (lane == 0) { s_w[wid] = xs; s_w[16 + wid] = xq; }
  __syncthreads();  // B3
  float sm = 0.0f, sq = 0.0f;
  #pragma unroll
  for (int w = 0; w < 16; ++w) { sm += s_w[w]; sq += s_w[16 + w]; }
  const float mu_ = sm / (float)DIN_;
  const float var = sq / (float)DIN_ - mu_ * mu_;
  const float inv = 1.0f / sqrtf(var + 1e-5f);

  // ReLU write + x0 compaction ballot (fused)
  bool nzp0 = false;
  if (t < DIN_) {
    const float y = fmaxf((s_x0[t] - mu_) * inv * ln_g[t] + ln_b[t], 0.0f);
    s_x0[t] = y;
    nzp0 = (y > 0.0f);
  }
  int rank0;
  {
    const unsigned long long mk = __ballot(nzp0);
    rank0 = (int)__popcll(mk & ((1ULL << lane) - 1ULL));
    if (lane == 0) s_cnt[wid] = (int)__popcll(mk);
  }
  __syncthreads();  // B4: s_x0 + s_cnt
  int nnz0 = 0, woff0 = 0;
  #pragma unroll
  for (int w = 0; w < 16; ++w) {
    if (w < wid) woff0 += s_cnt[w];
    nnz0 += s_cnt[w];
  }
  if (nzp0) s_idx0[woff0 + rank0] = t;
  __syncthreads();  // B5: idx0 ready

  // ---- FC1 640->512 over nonzero rows ----
  {
    const int fg = t & 127;
    const int sl = t >> 7;
    const int chunk = (nnz0 + 7) >> 3;
    const int i0 = sl * chunk;
    const int i1 = min(i0 + chunk, nnz0);
    float4 a = make_float4(0.f, 0.f, 0.f, 0.f);
    for (int i = i0; i < i1; ++i) {
      const int r = s_idx0[i];
      const float xv = s_x0[r];
      const float4 w = reinterpret_cast<const float4*>(W1 + (size_t)r * H1_)[fg];
      a.x = fmaf(xv, w.x, a.x);
      a.y = fmaf(xv, w.y, a.y);
      a.z = fmaf(xv, w.z, a.z);
      a.w = fmaf(xv, w.w, a.w);
    }
    reinterpret_cast<float4*>(s_fc)[sl * 128 + fg] = a;
  }
  __syncthreads();  // B6: FC1 partials

  // x1 write + compaction ballot (fused)
  bool nzp1 = false;
  if (t < H1_) {
    float acc = 0.0f;
    #pragma unroll
    for (int sl = 0; sl < 8; ++sl) acc += s_fc[sl * 512 + t];
    const float y = fmaxf(acc + b1[t], 0.0f);
    s_x1[t] = y;
    nzp1 = (y > 0.0f);
  }
  int rank1;
  {
    const unsigned long long mk = __ballot(nzp1);
    rank1 = (int)__popcll(mk & ((1ULL << lane) - 1ULL));
    if (lane == 0) s_cnt[wid] = (int)__popcll(mk);
  }
  __syncthreads();  // B7
  int nnz1 = 0, woff1 = 0;
  #pragma unroll
  for (int w = 0; w < 16; ++w) {
    if (w < wid) woff1 += s_cnt[w];
    nnz1 += s_cnt[w];
  }
  if (nzp1) s_idx1[woff1 + rank1] = t;
  __syncthreads();  // B8

  // ---- FC2 512->256 over nonzero rows + W3 dot ----
  {
    const int fg = t & 63;
    const int sl = t >> 6;
    const int chunk = (nnz1 + 15) >> 4;
    const int i0 = sl * chunk;
    const int i1 = min(i0 + chunk, nnz1);
    float4 a = make_float4(0.f, 0.f, 0.f, 0.f);
    for (int i = i0; i < i1; ++i) {
      const int r = s_idx1[i];
      const float xv = s_x1[r];
      const float4 w = reinterpret_cast<const float4*>(W2 + (size_t)r * H2_)[fg];
      a.x = fmaf(xv, w.x, a.x);
      a.y = fmaf(xv, w.y, a.y);
      a.z = fmaf(xv, w.z, a.z);
      a.w = fmaf(xv, w.w, a.w);
    }
    reinterpret_cast<float4*>(s_fc)[sl * 64 + fg] = a;
  }
  __syncthreads();  // B9

  float contrib = 0.0f;
  if (t < H2_) {
    float acc = 0.0f;
    #pragma unroll
    for (int sl = 0; sl < 16; ++sl) acc += s_fc[sl * 256 + t];
    contrib = fmaxf(acc + b2[t], 0.0f) * W3[t];
  }
  contrib = wave_sum(contrib);
  if (lane == 0 && wid < 4) s_w[32 + wid] = contrib;
  __syncthreads();  // B10
  if (t == 0)
    out[b] = ((s_w[32] + s_w[33]) + (s_w[34] + s_w[35])) + b3[0];
}

extern "C" void kernel_launch(void* const* d_in, const int* in_sizes, int n_in,
                              void* d_out, int out_size, void* d_ws, size_t ws_size,
                              hipStream_t stream) {
  const float* X     = (const float*)d_in[0];
  const int*   mpos  = (const int*)  d_in[6];
  const int*   mwt   = (const int*)  d_in[7];
  const int*   mmut  = (const int*)  d_in[8];
  const float* hid1  = (const float*)d_in[11];
  const float* hid2  = (const float*)d_in[12];
  const float* memb  = (const float*)d_in[13];
  const float* edges = (const float*)d_in[14];
  const float* Wse   = (const float*)d_in[15];
  const float* ln_g  = (const float*)d_in[16];
  const float* ln_b  = (const float*)d_in[17];
  const float* W1    = (const float*)d_in[18];
  const float* b1    = (const float*)d_in[19];
  const float* W2    = (const float*)d_in[20];
  const float* b2    = (const float*)d_in[21];
  const float* W3    = (const float*)d_in[22];
  const float* b3    = (const float*)d_in[23];

  float* out = (float*)d_out;  // [16]

  k_fused<<<BB, NT, 0, stream>>>(X, mpos, mwt, mmut, hid1, hid2, memb, edges,
                                 Wse, ln_g, ln_b, W1, b1, W2, b2, W3, b3, out);
}